// Round 6
// baseline (1344.793 us; speedup 1.0000x reference)
//
#include <hip/hip_runtime.h>
#include <hip/hip_bf16.h>
#include <stdint.h>

// Problem constants (fixed by the reference)
#define NB 16
#define NN 4096
#define NCF 64
#define NS 1024
#define NK 32
#define NPTS (NB*NS*NK)   // 524288
#define CIN 67
#define EPSV 1e-5f

// rn intrinsics: block FMA contraction so FPS/kNN distances bit-match numpy
static __device__ __forceinline__ float fmul(float a, float b){ return __fmul_rn(a,b); }
static __device__ __forceinline__ float fadd(float a, float b){ return __fadd_rn(a,b); }
static __device__ __forceinline__ float fsub(float a, float b){ return __fsub_rn(a,b); }

typedef float f2 __attribute__((ext_vector_type(2)));
// Packed f32 ops (VOP3P, CDNA): per-element semantics identical to the scalar
// ops (rn add/mul, fused fma). Only add/mul/fma exist packed — no pk_min/max.
#define PK_ADD(d,a,b) asm("v_pk_add_f32 %0, %1, %2" : "=v"(d) : "v"(a), "v"(b))
#define PK_MUL(d,a,b) asm("v_pk_mul_f32 %0, %1, %2" : "=v"(d) : "v"(a), "v"(b))
#define PK_FMA(d,a,b) asm("v_pk_fma_f32 %0, %1, %2, %0" : "+v"(d) : "v"(a), "v"(b))
static __device__ __forceinline__ f2 pk_add(f2 a, f2 b){ f2 d; PK_ADD(d,a,b); return d; }
static __device__ __forceinline__ f2 pk_mul(f2 a, f2 b){ f2 d; PK_MUL(d,a,b); return d; }

static __device__ __forceinline__ unsigned short f2b(float f){
  unsigned u = __float_as_uint(f);
  return (unsigned short)((u + 0x7FFFu + ((u>>16)&1u)) >> 16);  // RNE bf16
}

static __device__ __forceinline__ unsigned long long umax64(unsigned long long a,
                                                            unsigned long long b){
  return a > b ? a : b;
}

// ---- DPP cross-lane reductions (pure VALU — no LDS latency) ----------------
template<int CTRL>
static __device__ __forceinline__ float dppmax_f32(float x){
  float o = __uint_as_float((unsigned)__builtin_amdgcn_update_dpp(
      0, (int)__float_as_uint(x), CTRL, 0xf, 0xf, true));
  return fmaxf(x, o);
}
// full-wave max -> valid in lane 63
static __device__ __forceinline__ float wave_max63_f32(float x){
  x = dppmax_f32<0x111>(x);  // row_shr:1
  x = dppmax_f32<0x112>(x);  // row_shr:2
  x = dppmax_f32<0x114>(x);  // row_shr:4
  x = dppmax_f32<0x118>(x);  // row_shr:8
  x = dppmax_f32<0x142>(x);  // row_bcast:15
  x = dppmax_f32<0x143>(x);  // row_bcast:31
  return x;
}
// 8-lane-group max, result in ALL 8 lanes (quad_perm xor1, xor2, half_mirror)
static __device__ __forceinline__ float group8_max_f32(float x){
  x = dppmax_f32<0xB1>(x);   // quad_perm [1,0,3,2]
  x = dppmax_f32<0x4E>(x);   // quad_perm [2,3,0,1]
  x = dppmax_f32<0x141>(x);  // row_half_mirror
  return x;
}
// packed f2 DPP add stage: 2 dpp movs + 1 pk_add
template<int CTRL>
static __device__ __forceinline__ f2 dppadd_f2(f2 x){
  f2 o;
  o.x = __uint_as_float((unsigned)__builtin_amdgcn_update_dpp(
      0, (int)__float_as_uint(x.x), CTRL, 0xf, 0xf, true));
  o.y = __uint_as_float((unsigned)__builtin_amdgcn_update_dpp(
      0, (int)__float_as_uint(x.y), CTRL, 0xf, 0xf, true));
  return pk_add(x, o);
}
// full-wave packed sum -> valid in lane 63
static __device__ __forceinline__ f2 wave_sum63_f2(f2 x){
  x = dppadd_f2<0x111>(x);
  x = dppadd_f2<0x112>(x);
  x = dppadd_f2<0x114>(x);
  x = dppadd_f2<0x118>(x);
  x = dppadd_f2<0x142>(x);
  x = dppadd_f2<0x143>(x);
  return x;
}
// 32-half packed sum -> valid in lanes 31 and 63
static __device__ __forceinline__ f2 half_sum31_f2(f2 x){
  x = dppadd_f2<0x111>(x);
  x = dppadd_f2<0x112>(x);
  x = dppadd_f2<0x114>(x);
  x = dppadd_f2<0x118>(x);
  x = dppadd_f2<0x142>(x);
  return x;
}
static __device__ __forceinline__ unsigned long long readlane_u64(unsigned long long v, int l){
  unsigned lo = (unsigned)__builtin_amdgcn_readlane((int)(unsigned)v, l);
  unsigned hi = (unsigned)__builtin_amdgcn_readlane((int)(unsigned)(v>>32), l);
  return ((unsigned long long)hi<<32) | lo;
}
// whole-wave shift toward higher lanes by 1 (DPP wave_shr:1); lane0 <- 0
static __device__ __forceinline__ unsigned long long wave_shr1_u64(unsigned long long x){
  unsigned lo = (unsigned)__builtin_amdgcn_update_dpp(
      0, (int)(unsigned)x, 0x138, 0xf, 0xf, true);
  unsigned hi = (unsigned)__builtin_amdgcn_update_dpp(
      0, (int)(unsigned)(x>>32), 0x138, 0xf, 0xf, true);
  return ((unsigned long long)hi<<32) | lo;
}

// ---------------------------------------------------------------------------
// prep: transpose points (B,CF,N)->(B,N,CF) and compute sq_xyz with rn ops
// ---------------------------------------------------------------------------
__global__ __launch_bounds__(256) void prep_kernel(const float* __restrict__ pts,
    const float* __restrict__ xyz, float* __restrict__ ptsT, float* __restrict__ sqx){
  int blk = blockIdx.x;            // 256 blocks = 16 b * 16 chunks
  int b = blk >> 4;
  int n = ((blk & 15) << 8) + threadIdx.x;
  const float* src = pts + (size_t)b*NCF*NN + n;
  float v[NCF];
  #pragma unroll
  for (int c=0;c<NCF;c++) v[c] = src[(size_t)c*NN];
  float4* dst = (float4*)(ptsT + ((size_t)b*NN + n)*NCF);
  #pragma unroll
  for (int j=0;j<16;j++) dst[j] = make_float4(v[4*j],v[4*j+1],v[4*j+2],v[4*j+3]);
  const float* xp = xyz + ((size_t)b*NN + n)*3;
  float x=xp[0], y=xp[1], z=xp[2];
  sqx[(size_t)b*NN+n] = fadd(fadd(fmul(x,x),fmul(y,y)),fmul(z,z));
}

// ---------------------------------------------------------------------------
// FPS: one block per batch, 512 threads = 8 waves = 2 waves/SIMD so a wave's
// serial reduce/barrier latency is hidden by the sibling wave's compute.
// CONTIGUOUS ownership: thread t owns [8t, 8t+8) -> lane order == n order.
// Per step: packed rn distance update (4 f2 pairs) -> per-lane (bv,bj) strict
// > -> DPP f32 max -> readlane(63) -> ballot tie -> lowest lane -> readlane(n)
// -> lane0 writes wave key (f32bits<<32 | ~n) to parity slot -> 1 barrier ->
// 4x b128 read of 8 keys + 7 umax -> s4[far]. np.argmax exact (tie->lowest n).
// ---------------------------------------------------------------------------
#define FT 512
__global__ __launch_bounds__(FT) void fps_kernel(const float* __restrict__ xyz,
    int* __restrict__ fidx, float* __restrict__ newxyz){
  int b = blockIdx.x;
  __shared__ float4 s4[NN];                       // 64 KB packed coords
  __shared__ unsigned long long candK[2][8];      // parity-double-buffered keys
  const int tid = threadIdx.x;
  const int lane = tid & 63;
  const int wv = tid >> 6;
  for (int i = tid; i < NN; i += FT){
    const float* p = xyz + ((size_t)b*NN + i)*3;
    s4[i] = make_float4(p[0], p[1], p[2], 0.f);
  }
  __syncthreads();
  // pair m: .x -> n = 8*tid + 2m, .y -> n = 8*tid + 2m + 1 (ascending)
  f2 px[4], py[4], pz[4], d2[4];
  #pragma unroll
  for (int m=0;m<4;m++){
    float4 a = s4[tid*8 + 2*m];
    float4 c = s4[tid*8 + 2*m + 1];
    px[m] = (f2){a.x, c.x};
    py[m] = (f2){a.y, c.y};
    pz[m] = (f2){a.z, c.z};
    d2[m] = (f2){1e10f, 1e10f};
  }
  int far = 0;
  float4 cc = s4[0];
  for (int s=0;s<NS;s++){
    if (tid==0){
      fidx[b*NS+s] = far;
      float* o = newxyz + ((size_t)b*NS+s)*3;
      o[0]=cc.x; o[1]=cc.y; o[2]=cc.z;
    }
    f2 ncx = (f2){-cc.x,-cc.x}, ncy = (f2){-cc.y,-cc.y}, ncz = (f2){-cc.z,-cc.z};
    float bv = -1.0f; int bj = 0;
    #pragma unroll
    for (int m=0;m<4;m++){
      f2 dx,dy,dz,xx,yy,zz,ss,dd;
      PK_ADD(dx, px[m], ncx);              // = p - c  (rn sub per element)
      PK_ADD(dy, py[m], ncy);
      PK_ADD(dz, pz[m], ncz);
      PK_MUL(xx, dx, dx);
      PK_MUL(yy, dy, dy);
      PK_ADD(ss, xx, yy);                  // (dx2+dy2)
      PK_MUL(zz, dz, dz);
      PK_ADD(dd, ss, zz);                  // +dz2 — numpy order, rn each
      float u0 = fminf(d2[m].x, dd.x);
      float u1 = fminf(d2[m].y, dd.y);
      d2[m].x = u0; d2[m].y = u1;
      if (u0 > bv){ bv = u0; bj = 2*m; }   // strict >: keeps lowest local n
      if (u1 > bv){ bv = u1; bj = 2*m+1; }
    }
    int nbest = (tid<<3) + bj;             // global n of this lane's winner
    float mv = wave_max63_f32(bv);
    float mvu = __uint_as_float((unsigned)__builtin_amdgcn_readlane(
        (int)__float_as_uint(mv), 63));
    unsigned long long tiedm = __ballot(bv == mvu);
    int wl = __ffsll(tiedm) - 1;           // lowest lane = lowest n (contiguous map)
    unsigned nwin = (unsigned)__builtin_amdgcn_readlane(nbest, wl);
    if (lane == 0)
      candK[s&1][wv] = ((unsigned long long)__float_as_uint(mvu) << 32)
                     | (unsigned long long)(unsigned)~nwin;
    __syncthreads();
    const ulonglong2* cp = (const ulonglong2*)candK[s&1];
    ulonglong2 c0=cp[0], c1=cp[1], c2=cp[2], c3=cp[3];
    unsigned long long kk = umax64(
        umax64(umax64(c0.x,c0.y), umax64(c1.x,c1.y)),
        umax64(umax64(c2.x,c2.y), umax64(c3.x,c3.y)));
    far = (int)(~(unsigned)kk) & (NN-1);
    cc = s4[far];
  }
}

__global__ __launch_bounds__(256) void dcen_kernel(const float* __restrict__ density,
    const int* __restrict__ fidx, float* __restrict__ dcen){
  int i = blockIdx.x*256 + threadIdx.x;   // 16384
  int b = i >> 10;
  dcen[i] = density[(size_t)b*NN + fidx[i]];
}

__global__ __launch_bounds__(256) void dstats_kernel(const float* __restrict__ dcen,
    float* __restrict__ dstat){
  float s=0.f, q=0.f;
  for (int i=threadIdx.x; i<NB*NS; i+=256){ float v=dcen[i]; s+=v; q+=v*v; }
  __shared__ float ls[256], lq[256];
  ls[threadIdx.x]=s; lq[threadIdx.x]=q;
  __syncthreads();
  for (int off=128; off>0; off>>=1){
    if (threadIdx.x<off){ ls[threadIdx.x]+=ls[threadIdx.x+off]; lq[threadIdx.x]+=lq[threadIdx.x+off]; }
    __syncthreads();
  }
  if (threadIdx.x==0){
    float m = ls[0]/(float)(NB*NS);
    dstat[0]=m; dstat[1]=lq[0]/(float)(NB*NS) - m*m;
  }
}

// ---------------------------------------------------------------------------
// kNN: one wave per center; top-32 kept SORTED ASCENDING across lanes 0..31
// (key = sortable(d)<<32 | n -> exact (d,n) lex order; keys unique via n).
// Insertion: v_cmp_gt_u64 + ballot + DPP wave_shr:1 + cndmask + readlane(31).
// Lanes 32..63 hold junk shifted past lane 31 (ignored). Neighbor ORDER
// irrelevant downstream (perm-invariant MLP+max), only the SET matters.
// ---------------------------------------------------------------------------
__global__ __launch_bounds__(256) void knn_kernel(const float* __restrict__ xyz,
    const float* __restrict__ sqx, const float* __restrict__ newxyz,
    int* __restrict__ kidx){
  const int lane = threadIdx.x & 63;
  const int g = blockIdx.x*4 + (threadIdx.x >> 6);
  const int b = g >> 10;
  const float* cp = newxyz + (size_t)g*3;
  const float cx=cp[0], cy=cp[1], cz=cp[2];
  const float sqc = fadd(fadd(fmul(cx,cx),fmul(cy,cy)),fmul(cz,cz));
  const float* xb  = xyz + (size_t)b*NN*3;
  const float* sqb = sqx + (size_t)b*NN;
  unsigned long long kept  = ~0ULL;     // all slots empty (= +inf key)
  unsigned long long worst = ~0ULL;     // kept[31]
  for (int n0=0; n0<NN; n0+=64){
    const int n = n0 + lane;
    const float* xp = xb + (size_t)n*3;
    float x=xp[0], y=xp[1], z=xp[2];
    float dot = fadd(fadd(fmul(cx,x),fmul(cy,y)),fmul(cz,z));
    float d = fsub(fadd(sqc, sqb[n]), fmul(2.0f,dot));
    unsigned u = __float_as_uint(d);
    u = (u & 0x80000000u) ? ~u : (u | 0x80000000u);   // total order incl. negatives
    unsigned long long ck = ((unsigned long long)u << 32) | (unsigned)n;
    unsigned long long mask = __ballot(ck < worst);
    while (mask){
      const int l = __ffsll(mask) - 1;
      mask &= mask - 1;
      const unsigned long long k = readlane_u64(ck, l);
      if (k < worst){                     // uniform across wave
        bool m = kept > k;                // lanes >= insertion position
        unsigned long long M = __ballot(m) << 1;
        unsigned long long sh = wave_shr1_u64(kept);
        bool msh = (M >> lane) & 1ULL;    // predecessor also shifted?
        unsigned long long ins = msh ? sh : k;
        kept = m ? ins : kept;
        worst = readlane_u64(kept, 31);
      }
    }
  }
  if (lane < 32) kidx[(size_t)g*NK + lane] = (int)(kept & 0xFFFFFFFFULL);
}

// ---------------------------------------------------------------------------
// conv1: block=256, 128 pts, 2pts x 16outs per thread; v_pk_fma_f32 inner
// (2 channels per inst), packed DPP sum tails.
// ---------------------------------------------------------------------------
__global__ __launch_bounds__(256) void conv1_kernel(const float* __restrict__ xyz,
    const float* __restrict__ ptsT, const float* __restrict__ newxyz,
    const int* __restrict__ kidx, const float* __restrict__ w0,
    const float* __restrict__ b0, unsigned short* __restrict__ z1,
    float* __restrict__ partial){
  __shared__ float si[CIN][128];
  __shared__ float sw[CIN][64];
  __shared__ float sbias[64];
  const int tid = threadIdx.x;
  for (int i = tid; i < CIN*64; i += 256){
    int o = i / CIN, c = i - o*CIN;
    sw[c][o] = w0[i];
  }
  if (tid < 64) sbias[tid] = b0[tid];
  const int p0 = blockIdx.x * 128;
  if (tid < 128){
    const int p = p0 + tid;
    const int g = p >> 5;
    const int b = g >> 10;
    const int n = kidx[p];
    const float* xp = xyz + ((size_t)b*NN + n)*3;
    const float* cp = newxyz + (size_t)g*3;
    si[0][tid] = xp[0]-cp[0];
    si[1][tid] = xp[1]-cp[1];
    si[2][tid] = xp[2]-cp[2];
    const float4* pr = (const float4*)(ptsT + ((size_t)b*NN + n)*NCF);
    #pragma unroll
    for (int j=0;j<16;j++){
      float4 v = pr[j];
      si[3+4*j][tid]=v.x; si[4+4*j][tid]=v.y; si[5+4*j][tid]=v.z; si[6+4*j][tid]=v.w;
    }
  }
  __syncthreads();
  const int og = tid >> 6;     // wave id, 16 outputs (8 f2 pairs)
  const int pg = tid & 63;     // 2 points
  f2 acc0[8], acc1[8];
  const f2* bp = (const f2*)&sbias[og*16];
  #pragma unroll
  for (int q=0;q<8;q++){ f2 bb = bp[q]; acc0[q]=bb; acc1[q]=bb; }
  for (int c=0;c<CIN;c++){
    float2 a = *(const float2*)&si[c][2*pg];
    const f2* wr = (const f2*)&sw[c][og*16];
    f2 a0 = (f2){a.x, a.x};
    f2 a1 = (f2){a.y, a.y};
    #pragma unroll
    for (int q=0;q<8;q++){
      f2 w = wr[q];
      PK_FMA(acc0[q], a0, w);
      PK_FMA(acc1[q], a1, w);
    }
  }
  unsigned v[8];
  #pragma unroll
  for (int j=0;j<8;j++) v[j] = (unsigned)f2b(acc0[j].x) | ((unsigned)f2b(acc0[j].y)<<16);
  uint4* d0 = (uint4*)(z1 + (size_t)(p0+2*pg)*64 + og*16);
  d0[0]=make_uint4(v[0],v[1],v[2],v[3]); d0[1]=make_uint4(v[4],v[5],v[6],v[7]);
  #pragma unroll
  for (int j=0;j<8;j++) v[j] = (unsigned)f2b(acc1[j].x) | ((unsigned)f2b(acc1[j].y)<<16);
  uint4* d1 = (uint4*)(z1 + (size_t)(p0+2*pg+1)*64 + og*16);
  d1[0]=make_uint4(v[0],v[1],v[2],v[3]); d1[1]=make_uint4(v[4],v[5],v[6],v[7]);
  #pragma unroll
  for (int q=0;q<8;q++){
    f2 s = pk_add(acc0[q], acc1[q]);
    f2 sq = pk_add(pk_mul(acc0[q],acc0[q]), pk_mul(acc1[q],acc1[q]));
    s = wave_sum63_f2(s);
    sq = wave_sum63_f2(sq);
    if (pg==63){
      float* pb = partial + (size_t)blockIdx.x*128 + og*16;
      pb[2*q]=s.x; pb[2*q+1]=s.y;
      pb[64+2*q]=sq.x; pb[64+2*q+1]=sq.y;
    }
  }
}

__global__ __launch_bounds__(256) void conv2_kernel(const unsigned short* __restrict__ z1,
    const float* __restrict__ w1, const float* __restrict__ b1,
    const float* __restrict__ scale1, const float* __restrict__ shift1,
    unsigned short* __restrict__ z2, float* __restrict__ partial){
  __shared__ float si[64][128];
  __shared__ float sw[64][64];
  __shared__ float sbias[64];
  const int tid = threadIdx.x;
  for (int i = tid; i < 64*64; i += 256){
    int o = i >> 6, c = i & 63;
    sw[c][o] = w1[i];
  }
  if (tid < 64) sbias[tid] = b1[tid];
  const int p0 = blockIdx.x * 128;
  if (tid < 128){
    const uint4* zr = (const uint4*)(z1 + (size_t)(p0 + tid)*64);
    #pragma unroll
    for (int j=0;j<8;j++){
      uint4 vv = zr[j];
      unsigned a[4] = {vv.x, vv.y, vv.z, vv.w};
      #pragma unroll
      for (int t=0;t<4;t++){
        int c = j*8 + t*2;
        float lo = __uint_as_float(a[t] << 16);
        float hi = __uint_as_float(a[t] & 0xFFFF0000u);
        si[c][tid]   = fmaxf(lo*scale1[c]   + shift1[c],   0.0f);
        si[c+1][tid] = fmaxf(hi*scale1[c+1] + shift1[c+1], 0.0f);
      }
    }
  }
  __syncthreads();
  const int og = tid >> 6;
  const int pg = tid & 63;
  f2 acc0[8], acc1[8];
  const f2* bp = (const f2*)&sbias[og*16];
  #pragma unroll
  for (int q=0;q<8;q++){ f2 bb = bp[q]; acc0[q]=bb; acc1[q]=bb; }
  for (int c=0;c<64;c++){
    float2 a = *(const float2*)&si[c][2*pg];
    const f2* wr = (const f2*)&sw[c][og*16];
    f2 a0 = (f2){a.x, a.x};
    f2 a1 = (f2){a.y, a.y};
    #pragma unroll
    for (int q=0;q<8;q++){
      f2 w = wr[q];
      PK_FMA(acc0[q], a0, w);
      PK_FMA(acc1[q], a1, w);
    }
  }
  unsigned v[8];
  #pragma unroll
  for (int j=0;j<8;j++) v[j] = (unsigned)f2b(acc0[j].x) | ((unsigned)f2b(acc0[j].y)<<16);
  uint4* d0 = (uint4*)(z2 + (size_t)(p0+2*pg)*64 + og*16);
  d0[0]=make_uint4(v[0],v[1],v[2],v[3]); d0[1]=make_uint4(v[4],v[5],v[6],v[7]);
  #pragma unroll
  for (int j=0;j<8;j++) v[j] = (unsigned)f2b(acc1[j].x) | ((unsigned)f2b(acc1[j].y)<<16);
  uint4* d1 = (uint4*)(z2 + (size_t)(p0+2*pg+1)*64 + og*16);
  d1[0]=make_uint4(v[0],v[1],v[2],v[3]); d1[1]=make_uint4(v[4],v[5],v[6],v[7]);
  #pragma unroll
  for (int q=0;q<8;q++){
    f2 s = pk_add(acc0[q], acc1[q]);
    f2 sq = pk_add(pk_mul(acc0[q],acc0[q]), pk_mul(acc1[q],acc1[q]));
    s = wave_sum63_f2(s);
    sq = wave_sum63_f2(sq);
    if (pg==63){
      float* pb = partial + (size_t)blockIdx.x*128 + og*16;
      pb[2*q]=s.x; pb[2*q+1]=s.y;
      pb[64+2*q]=sq.x; pb[64+2*q+1]=sq.y;
    }
  }
}

// conv3: 128 pts (4 centers)/block, 4pts x 16outs per thread; pk_fma inner,
// scalar DPP max (no pk_max_f32 on CDNA), packed DPP sum tails.
// Max over k fused pre-BN (BN3 scale>0, density weight>=0).
__global__ __launch_bounds__(256) void conv3_kernel(const unsigned short* __restrict__ z2,
    const float* __restrict__ w2, const float* __restrict__ b2,
    const float* __restrict__ scale2, const float* __restrict__ shift2,
    float* __restrict__ m3, float* __restrict__ partial){
  __shared__ float si[64][128];
  __shared__ float sw[64][128];
  const int tid = threadIdx.x;
  for (int i = tid; i < 64*128; i += 256){
    int o = i >> 6, c = i & 63;
    sw[c][o] = w2[i];
  }
  const int p0 = blockIdx.x * 128;     // grid 4096
  if (tid < 128){
    const uint4* zr = (const uint4*)(z2 + (size_t)(p0 + tid)*64);
    #pragma unroll
    for (int j=0;j<8;j++){
      uint4 vv = zr[j];
      unsigned a[4]={vv.x,vv.y,vv.z,vv.w};
      #pragma unroll
      for (int t=0;t<4;t++){
        int c = j*8+t*2;
        float lo=__uint_as_float(a[t]<<16), hi=__uint_as_float(a[t]&0xFFFF0000u);
        si[c][tid]   = fmaxf(lo*scale2[c]+shift2[c],0.f);
        si[c+1][tid] = fmaxf(hi*scale2[c+1]+shift2[c+1],0.f);
      }
    }
  }
  __syncthreads();
  const int og = tid >> 5;    // 0..7 -> outputs og*16..+15 (8 f2 pairs)
  const int pg = tid & 31;    // 4 pts: p0 + pg*4 .. +3 (center = pg>>3)
  f2 acc[4][8];
  const f2* bq = (const f2*)(b2 + og*16);
  #pragma unroll
  for (int q=0;q<8;q++){
    f2 bb = bq[q];
    #pragma unroll
    for (int p=0;p<4;p++) acc[p][q]=bb;
  }
  for (int c=0;c<64;c++){
    float4 a = *(const float4*)&si[c][pg*4];
    const f2* wr = (const f2*)&sw[c][og*16];
    f2 a0=(f2){a.x,a.x}, a1=(f2){a.y,a.y}, a2=(f2){a.z,a.z}, a3=(f2){a.w,a.w};
    #pragma unroll
    for (int q=0;q<8;q++){
      f2 w = wr[q];
      PK_FMA(acc[0][q], a0, w);
      PK_FMA(acc[1][q], a1, w);
      PK_FMA(acc[2][q], a2, w);
      PK_FMA(acc[3][q], a3, w);
    }
  }
  float mx[16];
  #pragma unroll
  for (int q=0;q<8;q++){
    float mxx = fmaxf(fmaxf(acc[0][q].x,acc[1][q].x), fmaxf(acc[2][q].x,acc[3][q].x));
    float mxy = fmaxf(fmaxf(acc[0][q].y,acc[1][q].y), fmaxf(acc[2][q].y,acc[3][q].y));
    mx[2*q]   = group8_max_f32(mxx);   // 8-lane group = 1 center
    mx[2*q+1] = group8_max_f32(mxy);
  }
  if ((pg & 7)==0){
    const int center = blockIdx.x*4 + (pg>>3);
    float4* mp = (float4*)(m3 + (size_t)center*128 + og*16);
    #pragma unroll
    for (int q=0;q<4;q++) mp[q] = make_float4(mx[4*q],mx[4*q+1],mx[4*q+2],mx[4*q+3]);
  }
  #pragma unroll
  for (int q=0;q<8;q++){
    f2 s = pk_add(pk_add(acc[0][q],acc[1][q]), pk_add(acc[2][q],acc[3][q]));
    f2 sq = pk_add(pk_add(pk_mul(acc[0][q],acc[0][q]), pk_mul(acc[1][q],acc[1][q])),
                   pk_add(pk_mul(acc[2][q],acc[2][q]), pk_mul(acc[3][q],acc[3][q])));
    s = half_sum31_f2(s);
    sq = half_sum31_f2(sq);
    if (pg==31){
      float* pb = partial + (size_t)blockIdx.x*256 + og*16;
      pb[2*q]=s.x; pb[2*q+1]=s.y;
      pb[128+2*q]=sq.x; pb[128+2*q+1]=sq.y;
    }
  }
}

// reduce per-block partials -> BN scale/shift per channel (one block per channel)
__global__ __launch_bounds__(256) void mkbn_kernel(const float* __restrict__ partial,
    int nrows, int stride, const float* __restrict__ g, const float* __restrict__ be,
    float* __restrict__ scale, float* __restrict__ shift, float inv_count){
  const int c = blockIdx.x;
  const int C = gridDim.x;
  float s=0.f, q=0.f;
  for (int r=threadIdx.x; r<nrows; r+=256){
    s += partial[(size_t)r*stride + c];
    q += partial[(size_t)r*stride + C + c];
  }
  __shared__ float ls[256], lq[256];
  ls[threadIdx.x]=s; lq[threadIdx.x]=q;
  __syncthreads();
  for (int off=128; off>0; off>>=1){
    if (threadIdx.x < off){ ls[threadIdx.x]+=ls[threadIdx.x+off]; lq[threadIdx.x]+=lq[threadIdx.x+off]; }
    __syncthreads();
  }
  if (threadIdx.x==0){
    float mean = ls[0]*inv_count;
    float var  = lq[0]*inv_count - mean*mean;
    float sc = g[c]*rsqrtf(var + EPSV);
    scale[c]=sc; shift[c]=be[c]-mean*sc;
  }
}

// out[b,ch,s] = relu(scale3*maxz + shift3) * relu(bn_d(wd*dcen+bd))
__global__ __launch_bounds__(256) void final_kernel(const float* __restrict__ m3,
    const float* __restrict__ dcen, const float* __restrict__ scale3,
    const float* __restrict__ shift3, const float* __restrict__ wd,
    const float* __restrict__ bd, const float* __restrict__ gd,
    const float* __restrict__ bed, const float* __restrict__ dstat,
    float* __restrict__ out){
  size_t i = (size_t)blockIdx.x*256 + threadIdx.x;   // 2,097,152 = b*2^17 + ch*2^10 + s
  int s  = (int)(i & 1023);
  int ch = (int)((i >> 10) & 127);
  int b  = (int)(i >> 17);
  float mean_d = dstat[0], var_d = dstat[1];
  float w = wd[ch];
  float meanp = w*mean_d + bd[ch];
  float varp  = w*w*var_d;          // var of affine(dcen): exact algebraic identity
  float dsc = gd[ch]*rsqrtf(varp + EPSV);
  float dsh = bed[ch] - meanp*dsc;
  float pre = w*dcen[b*NS+s] + bd[ch];
  float dw  = fmaxf(dsc*pre + dsh, 0.0f);
  float z   = m3[((size_t)(b*NS+s))*128 + ch];
  float x   = fmaxf(scale3[ch]*z + shift3[ch], 0.0f);
  out[i] = x*dw;
}

// ---------------------------------------------------------------------------
extern "C" void kernel_launch(void* const* d_in, const int* in_sizes, int n_in,
                              void* d_out, int out_size, void* d_ws, size_t ws_size,
                              hipStream_t stream){
  const float* xyz     = (const float*)d_in[0];
  const float* points  = (const float*)d_in[1];
  const float* density = (const float*)d_in[2];
  const float* w0 = (const float*)d_in[3];
  const float* b0 = (const float*)d_in[4];
  const float* g0 = (const float*)d_in[5];
  const float* be0= (const float*)d_in[6];
  const float* w1 = (const float*)d_in[7];
  const float* b1 = (const float*)d_in[8];
  const float* g1 = (const float*)d_in[9];
  const float* be1= (const float*)d_in[10];
  const float* w2 = (const float*)d_in[11];
  const float* b2 = (const float*)d_in[12];
  const float* g2 = (const float*)d_in[13];
  const float* be2= (const float*)d_in[14];
  const float* wd = (const float*)d_in[15];
  const float* bd = (const float*)d_in[16];
  const float* gd = (const float*)d_in[17];
  const float* bed= (const float*)d_in[18];

  float* out = (float*)d_out;
  float* newxyz = out;                 // (B,S,3) = output 0
  float* out1   = out + (size_t)NB*NS*3;

  // workspace layout (~174 MB total)
  float* ptsT = (float*)d_ws;                            // 4,194,304 f
  float* sqx  = ptsT + (size_t)NB*NN*NCF;                // 65,536 f
  int*   fidx = (int*)(sqx + (size_t)NB*NN);             // 16,384 i
  float* dcen = (float*)(fidx + NB*NS);                  // 16,384 f
  int*   kidx = (int*)(dcen + NB*NS);                    // 524,288 i
  unsigned short* z1 = (unsigned short*)(kidx + NPTS);   // 33,554,432 us
  unsigned short* z2 = z1 + (size_t)NPTS*64;             // 33,554,432 us
  float* m3   = (float*)(z2 + (size_t)NPTS*64);          // 2,097,152 f
  float* p1   = m3 + (size_t)NB*NS*128;                  // 4096*128 f
  float* p2   = p1 + 4096*128;                           // 4096*128 f
  float* p3   = p2 + 4096*128;                           // 4096*256 f
  float* bnp  = p3 + 4096*256;                           // 512 f (scale/shift x3)
  float* dstat= bnp + 512;                               // 2 f

  hipLaunchKernelGGL(prep_kernel,  dim3(256),  dim3(256), 0, stream, points, xyz, ptsT, sqx);
  hipLaunchKernelGGL(fps_kernel,   dim3(NB),   dim3(FT),  0, stream, xyz, fidx, newxyz);
  hipLaunchKernelGGL(dcen_kernel,  dim3(64),   dim3(256), 0, stream, density, fidx, dcen);
  hipLaunchKernelGGL(dstats_kernel,dim3(1),    dim3(256), 0, stream, dcen, dstat);
  hipLaunchKernelGGL(knn_kernel,   dim3(4096), dim3(256), 0, stream, xyz, sqx, newxyz, kidx);
  hipLaunchKernelGGL(conv1_kernel, dim3(4096), dim3(256), 0, stream, xyz, ptsT, newxyz, kidx, w0, b0, z1, p1);
  hipLaunchKernelGGL(mkbn_kernel,  dim3(64),   dim3(256), 0, stream, p1, 4096, 128, g0, be0, bnp+0,   bnp+64,  1.0f/(float)NPTS);
  hipLaunchKernelGGL(conv2_kernel, dim3(4096), dim3(256), 0, stream, z1, w1, b1, bnp+0, bnp+64, z2, p2);
  hipLaunchKernelGGL(mkbn_kernel,  dim3(64),   dim3(256), 0, stream, p2, 4096, 128, g1, be1, bnp+128, bnp+192, 1.0f/(float)NPTS);
  hipLaunchKernelGGL(conv3_kernel, dim3(4096), dim3(256), 0, stream, z2, w2, b2, bnp+128, bnp+192, m3, p3);
  hipLaunchKernelGGL(mkbn_kernel,  dim3(128),  dim3(256), 0, stream, p3, 4096, 256, g2, be2, bnp+256, bnp+384, 1.0f/(float)NPTS);
  hipLaunchKernelGGL(final_kernel, dim3(8192), dim3(256), 0, stream, m3, dcen, bnp+256, bnp+384, wd, bd, gd, bed, dstat, out1);
}

// Round 7
// 1136.638 us; speedup vs baseline: 1.1831x; 1.1831x over previous
//
#include <hip/hip_runtime.h>
#include <hip/hip_bf16.h>
#include <stdint.h>

// Problem constants (fixed by the reference)
#define NB 16
#define NN 4096
#define NCF 64
#define NS 1024
#define NK 32
#define NPTS (NB*NS*NK)   // 524288
#define CIN 67
#define EPSV 1e-5f

// rn intrinsics: block FMA contraction so FPS/kNN distances bit-match numpy
static __device__ __forceinline__ float fmul(float a, float b){ return __fmul_rn(a,b); }
static __device__ __forceinline__ float fadd(float a, float b){ return __fadd_rn(a,b); }
static __device__ __forceinline__ float fsub(float a, float b){ return __fsub_rn(a,b); }

typedef float f2 __attribute__((ext_vector_type(2)));
#define PK_ADD(d,a,b) asm("v_pk_add_f32 %0, %1, %2" : "=v"(d) : "v"(a), "v"(b))
#define PK_MUL(d,a,b) asm("v_pk_mul_f32 %0, %1, %2" : "=v"(d) : "v"(a), "v"(b))
static __device__ __forceinline__ f2 pk_add(f2 a, f2 b){ f2 d; PK_ADD(d,a,b); return d; }

// MFMA fragment types (gfx950 16x16x32 bf16: 8 bf16 in / 4 f32 acc per lane)
typedef short bf16x8 __attribute__((ext_vector_type(8)));
typedef float f32x4 __attribute__((ext_vector_type(4)));

static __device__ __forceinline__ unsigned short f2b(float f){
  unsigned u = __float_as_uint(f);
  return (unsigned short)((u + 0x7FFFu + ((u>>16)&1u)) >> 16);  // RNE bf16
}
static __device__ __forceinline__ unsigned pack2(float a, float b){
  return (unsigned)f2b(a) | ((unsigned)f2b(b)<<16);
}
static __device__ __forceinline__ unsigned long long umax64(unsigned long long a,
                                                            unsigned long long b){
  return a > b ? a : b;
}

// ---- DPP cross-lane reductions (pure VALU) ---------------------------------
template<int CTRL>
static __device__ __forceinline__ float dppmax_f32(float x){   // 0-fill (x>=0 only)
  float o = __uint_as_float((unsigned)__builtin_amdgcn_update_dpp(
      0, (int)__float_as_uint(x), CTRL, 0xf, 0xf, true));
  return fmaxf(x, o);
}
static __device__ __forceinline__ float wave_max63_f32(float x){
  x = dppmax_f32<0x111>(x); x = dppmax_f32<0x112>(x);
  x = dppmax_f32<0x114>(x); x = dppmax_f32<0x118>(x);
  x = dppmax_f32<0x142>(x); x = dppmax_f32<0x143>(x);
  return x;
}
// row-16 max keeping own value on invalid lanes (safe for negatives);
// valid in lane (row*16+15)
template<int CTRL>
static __device__ __forceinline__ float dppmax_keep(float x){
  float o = __uint_as_float((unsigned)__builtin_amdgcn_update_dpp(
      (int)__float_as_uint(x), (int)__float_as_uint(x), CTRL, 0xf, 0xf, false));
  return fmaxf(x, o);
}
static __device__ __forceinline__ float row16_max_f32(float x){
  x = dppmax_keep<0x111>(x); x = dppmax_keep<0x112>(x);
  x = dppmax_keep<0x114>(x); x = dppmax_keep<0x118>(x);
  return x;
}
template<int CTRL>
static __device__ __forceinline__ f2 dppadd_f2(f2 x){
  f2 o;
  o.x = __uint_as_float((unsigned)__builtin_amdgcn_update_dpp(
      0, (int)__float_as_uint(x.x), CTRL, 0xf, 0xf, true));
  o.y = __uint_as_float((unsigned)__builtin_amdgcn_update_dpp(
      0, (int)__float_as_uint(x.y), CTRL, 0xf, 0xf, true));
  return pk_add(x, o);
}
// row-16 sum -> valid in lane (row*16+15)
static __device__ __forceinline__ f2 row16_sum_f2(f2 x){
  x = dppadd_f2<0x111>(x); x = dppadd_f2<0x112>(x);
  x = dppadd_f2<0x114>(x); x = dppadd_f2<0x118>(x);
  return x;
}
static __device__ __forceinline__ unsigned long long readlane_u64(unsigned long long v, int l){
  unsigned lo = (unsigned)__builtin_amdgcn_readlane((int)(unsigned)v, l);
  unsigned hi = (unsigned)__builtin_amdgcn_readlane((int)(unsigned)(v>>32), l);
  return ((unsigned long long)hi<<32) | lo;
}
static __device__ __forceinline__ unsigned long long wave_shr1_u64(unsigned long long x){
  unsigned lo = (unsigned)__builtin_amdgcn_update_dpp(
      0, (int)(unsigned)x, 0x138, 0xf, 0xf, true);
  unsigned hi = (unsigned)__builtin_amdgcn_update_dpp(
      0, (int)(unsigned)(x>>32), 0x138, 0xf, 0xf, true);
  return ((unsigned long long)hi<<32) | lo;
}

// ---------------------------------------------------------------------------
// prep: transpose points (B,CF,N)->(B,N,CF) as BF16 + sq_xyz with rn ops
// ---------------------------------------------------------------------------
__global__ __launch_bounds__(256) void prep_kernel(const float* __restrict__ pts,
    const float* __restrict__ xyz, unsigned short* __restrict__ ptsT,
    float* __restrict__ sqx){
  int blk = blockIdx.x;            // 256 blocks = 16 b * 16 chunks
  int b = blk >> 4;
  int n = ((blk & 15) << 8) + threadIdx.x;
  const float* src = pts + (size_t)b*NCF*NN + n;
  float v[NCF];
  #pragma unroll
  for (int c=0;c<NCF;c++) v[c] = src[(size_t)c*NN];
  uint4* dst = (uint4*)(ptsT + ((size_t)b*NN + n)*NCF);
  #pragma unroll
  for (int j=0;j<8;j++)
    dst[j] = make_uint4(pack2(v[8*j],v[8*j+1]), pack2(v[8*j+2],v[8*j+3]),
                        pack2(v[8*j+4],v[8*j+5]), pack2(v[8*j+6],v[8*j+7]));
  const float* xp = xyz + ((size_t)b*NN + n)*3;
  float x=xp[0], y=xp[1], z=xp[2];
  sqx[(size_t)b*NN+n] = fadd(fadd(fmul(x,x),fmul(y,y)),fmul(z,z));
}

// ---------------------------------------------------------------------------
// FPS (unchanged from R6): 512 thr, contiguous ownership, DPP argmax,
// 1 barrier/step, parity-buffered per-wave keys. np.argmax exact.
// ---------------------------------------------------------------------------
#define FT 512
__global__ __launch_bounds__(FT) void fps_kernel(const float* __restrict__ xyz,
    int* __restrict__ fidx, float* __restrict__ newxyz){
  int b = blockIdx.x;
  __shared__ float4 s4[NN];
  __shared__ unsigned long long candK[2][8];
  const int tid = threadIdx.x;
  const int lane = tid & 63;
  const int wv = tid >> 6;
  for (int i = tid; i < NN; i += FT){
    const float* p = xyz + ((size_t)b*NN + i)*3;
    s4[i] = make_float4(p[0], p[1], p[2], 0.f);
  }
  __syncthreads();
  f2 px[4], py[4], pz[4], d2[4];
  #pragma unroll
  for (int m=0;m<4;m++){
    float4 a = s4[tid*8 + 2*m];
    float4 c = s4[tid*8 + 2*m + 1];
    px[m] = (f2){a.x, c.x};
    py[m] = (f2){a.y, c.y};
    pz[m] = (f2){a.z, c.z};
    d2[m] = (f2){1e10f, 1e10f};
  }
  int far = 0;
  float4 cc = s4[0];
  for (int s=0;s<NS;s++){
    if (tid==0){
      fidx[b*NS+s] = far;
      float* o = newxyz + ((size_t)b*NS+s)*3;
      o[0]=cc.x; o[1]=cc.y; o[2]=cc.z;
    }
    f2 ncx = (f2){-cc.x,-cc.x}, ncy = (f2){-cc.y,-cc.y}, ncz = (f2){-cc.z,-cc.z};
    float bv = -1.0f; int bj = 0;
    #pragma unroll
    for (int m=0;m<4;m++){
      f2 dx,dy,dz,xx,yy,zz,ss,dd;
      PK_ADD(dx, px[m], ncx);
      PK_ADD(dy, py[m], ncy);
      PK_ADD(dz, pz[m], ncz);
      PK_MUL(xx, dx, dx);
      PK_MUL(yy, dy, dy);
      PK_ADD(ss, xx, yy);
      PK_MUL(zz, dz, dz);
      PK_ADD(dd, ss, zz);                  // numpy order, rn each
      float u0 = fminf(d2[m].x, dd.x);
      float u1 = fminf(d2[m].y, dd.y);
      d2[m].x = u0; d2[m].y = u1;
      if (u0 > bv){ bv = u0; bj = 2*m; }
      if (u1 > bv){ bv = u1; bj = 2*m+1; }
    }
    int nbest = (tid<<3) + bj;
    float mv = wave_max63_f32(bv);
    float mvu = __uint_as_float((unsigned)__builtin_amdgcn_readlane(
        (int)__float_as_uint(mv), 63));
    unsigned long long tiedm = __ballot(bv == mvu);
    int wl = __ffsll(tiedm) - 1;
    unsigned nwin = (unsigned)__builtin_amdgcn_readlane(nbest, wl);
    if (lane == 0)
      candK[s&1][wv] = ((unsigned long long)__float_as_uint(mvu) << 32)
                     | (unsigned long long)(unsigned)~nwin;
    __syncthreads();
    const ulonglong2* cp = (const ulonglong2*)candK[s&1];
    ulonglong2 c0=cp[0], c1=cp[1], c2=cp[2], c3=cp[3];
    unsigned long long kk = umax64(
        umax64(umax64(c0.x,c0.y), umax64(c1.x,c1.y)),
        umax64(umax64(c2.x,c2.y), umax64(c3.x,c3.y)));
    far = (int)(~(unsigned)kk) & (NN-1);
    cc = s4[far];
  }
}

__global__ __launch_bounds__(256) void dcen_kernel(const float* __restrict__ density,
    const int* __restrict__ fidx, float* __restrict__ dcen){
  int i = blockIdx.x*256 + threadIdx.x;
  int b = i >> 10;
  dcen[i] = density[(size_t)b*NN + fidx[i]];
}

__global__ __launch_bounds__(256) void dstats_kernel(const float* __restrict__ dcen,
    float* __restrict__ dstat){
  float s=0.f, q=0.f;
  for (int i=threadIdx.x; i<NB*NS; i+=256){ float v=dcen[i]; s+=v; q+=v*v; }
  __shared__ float ls[256], lq[256];
  ls[threadIdx.x]=s; lq[threadIdx.x]=q;
  __syncthreads();
  for (int off=128; off>0; off>>=1){
    if (threadIdx.x<off){ ls[threadIdx.x]+=ls[threadIdx.x+off]; lq[threadIdx.x]+=lq[threadIdx.x+off]; }
    __syncthreads();
  }
  if (threadIdx.x==0){
    float m = ls[0]/(float)(NB*NS);
    dstat[0]=m; dstat[1]=lq[0]/(float)(NB*NS) - m*m;
  }
}

// ---------------------------------------------------------------------------
// kNN (unchanged from R5/R6 sorted-insert). Exact (d,n) lex order.
// ---------------------------------------------------------------------------
__global__ __launch_bounds__(256) void knn_kernel(const float* __restrict__ xyz,
    const float* __restrict__ sqx, const float* __restrict__ newxyz,
    int* __restrict__ kidx){
  const int lane = threadIdx.x & 63;
  const int g = blockIdx.x*4 + (threadIdx.x >> 6);
  const int b = g >> 10;
  const float* cp = newxyz + (size_t)g*3;
  const float cx=cp[0], cy=cp[1], cz=cp[2];
  const float sqc = fadd(fadd(fmul(cx,cx),fmul(cy,cy)),fmul(cz,cz));
  const float* xb  = xyz + (size_t)b*NN*3;
  const float* sqb = sqx + (size_t)b*NN;
  unsigned long long kept  = ~0ULL;
  unsigned long long worst = ~0ULL;
  for (int n0=0; n0<NN; n0+=64){
    const int n = n0 + lane;
    const float* xp = xb + (size_t)n*3;
    float x=xp[0], y=xp[1], z=xp[2];
    float dot = fadd(fadd(fmul(cx,x),fmul(cy,y)),fmul(cz,z));
    float d = fsub(fadd(sqc, sqb[n]), fmul(2.0f,dot));
    unsigned u = __float_as_uint(d);
    u = (u & 0x80000000u) ? ~u : (u | 0x80000000u);
    unsigned long long ck = ((unsigned long long)u << 32) | (unsigned)n;
    unsigned long long mask = __ballot(ck < worst);
    while (mask){
      const int l = __ffsll(mask) - 1;
      mask &= mask - 1;
      const unsigned long long k = readlane_u64(ck, l);
      if (k < worst){
        bool m = kept > k;
        unsigned long long M = __ballot(m) << 1;
        unsigned long long sh = wave_shr1_u64(kept);
        bool msh = (M >> lane) & 1ULL;
        unsigned long long ins = msh ? sh : k;
        kept = m ? ins : kept;
        worst = readlane_u64(kept, 31);
      }
    }
  }
  if (lane < 32) kidx[(size_t)g*NK + lane] = (int)(kept & 0xFFFFFFFFULL);
}

// ---------------------------------------------------------------------------
// MFMA convs. Layouts (gfx950 16x16x32 bf16, learn_hip-verified):
//   A[m=lane&15][k=(lane>>4)*8+j]   B[n=lane&15][k=(lane>>4)*8+j]
//   D: col(n)=lane&15, row(m)=(lane>>4)*4+reg
// LDS rows padded to 16B multiples; stats via row-16 DPP sums; conv3 k-max
// via row-16 DPP max (bound_ctrl=false).
// ---------------------------------------------------------------------------

// conv1: 128 pts/block, M=64 outs, K=96 (features k0..63, gxyz k64..66, 0-pad)
__global__ __launch_bounds__(256) void conv1_kernel(const float* __restrict__ xyz,
    const unsigned short* __restrict__ ptsT, const float* __restrict__ newxyz,
    const int* __restrict__ kidx, const float* __restrict__ w0,
    const float* __restrict__ b0, unsigned short* __restrict__ z1,
    float* __restrict__ partial){
  __shared__ unsigned short sa[128][104];   // inputs  (bf16), row=pt
  __shared__ unsigned short swb[64][104];   // weights (bf16), row=out
  const int tid = threadIdx.x;
  const int p0 = blockIdx.x * 128;
  // weights: k0..63 = w0[o][3+k]; k64..66 = w0[o][0..2]; k67..103 = 0
  for (int i = tid; i < 64*52; i += 256){
    int o = i / 52, pr = i - o*52, c0 = 2*pr;
    float v0 = (c0 < 64) ? w0[o*CIN + 3 + c0] : (c0 < 67 ? w0[o*CIN + (c0-64)] : 0.f);
    int c1 = c0 + 1;
    float v1 = (c1 < 64) ? w0[o*CIN + 3 + c1] : (c1 < 67 ? w0[o*CIN + (c1-64)] : 0.f);
    *(unsigned*)&swb[o][c0] = pack2(v0, v1);
  }
  // inputs: features (bf16 passthrough)
  #pragma unroll
  for (int j=0;j<4;j++){
    int idx = tid + j*256;            // 1024 = 128 pts x 8 groups
    int pt = idx >> 3, cg = idx & 7;
    int p = p0 + pt, g = p >> 5, b = g >> 10;
    int n = kidx[p];
    uint4 vv = *(const uint4*)(ptsT + ((size_t)b*NN + n)*NCF + cg*8);
    *(uint4*)&sa[pt][cg*8] = vv;
  }
  // inputs: geometry at k64..66, zeros 67..103
  if (tid < 128){
    int p = p0 + tid, g = p >> 5, b = g >> 10;
    int n = kidx[p];
    const float* xp = xyz + ((size_t)b*NN + n)*3;
    const float* cp = newxyz + (size_t)g*3;
    float gx = xp[0]-cp[0], gy = xp[1]-cp[1], gz = xp[2]-cp[2];
    *(uint2*)&sa[tid][64] = make_uint2(pack2(gx,gy), pack2(gz,0.f));
    *(uint2*)&sa[tid][68] = make_uint2(0u,0u);
    uint4 zz = make_uint4(0u,0u,0u,0u);
    *(uint4*)&sa[tid][72] = zz; *(uint4*)&sa[tid][80] = zz;
    *(uint4*)&sa[tid][88] = zz; *(uint4*)&sa[tid][96] = zz;
  }
  __syncthreads();
  const int wv = tid >> 6, lane = tid & 63;
  const int r15 = lane & 15, q = lane >> 4;
  f32x4 acc[8];
  #pragma unroll
  for (int t=0;t<8;t++) acc[t] = (f32x4){0.f,0.f,0.f,0.f};
  #pragma unroll
  for (int ks=0; ks<3; ks++){
    bf16x8 af = *(const bf16x8*)&swb[wv*16 + r15][ks*32 + q*8];
    #pragma unroll
    for (int t=0;t<8;t++){
      bf16x8 bfr = *(const bf16x8*)&sa[t*16 + r15][ks*32 + q*8];
      acc[t] = __builtin_amdgcn_mfma_f32_16x16x32_bf16(af, bfr, acc[t], 0,0,0);
    }
  }
  // epilogue: +bias, write z1 bf16, stats
  float bias[4];
  #pragma unroll
  for (int r=0;r<4;r++) bias[r] = b0[wv*16 + q*4 + r];
  f2 st[4];
  #pragma unroll
  for (int r=0;r<4;r++) st[r] = (f2){0.f,0.f};
  #pragma unroll
  for (int t=0;t<8;t++){
    float z0=acc[t][0]+bias[0], z1v=acc[t][1]+bias[1];
    float z2v=acc[t][2]+bias[2], z3v=acc[t][3]+bias[3];
    st[0] = pk_add(st[0], (f2){z0, z0*z0});
    st[1] = pk_add(st[1], (f2){z1v, z1v*z1v});
    st[2] = pk_add(st[2], (f2){z2v, z2v*z2v});
    st[3] = pk_add(st[3], (f2){z3v, z3v*z3v});
    *(uint2*)(z1 + (size_t)(p0 + t*16 + r15)*64 + wv*16 + q*4)
        = make_uint2(pack2(z0,z1v), pack2(z2v,z3v));
  }
  #pragma unroll
  for (int r=0;r<4;r++){
    f2 s = row16_sum_f2(st[r]);
    if (r15 == 15){
      int ch = wv*16 + q*4 + r;
      partial[(size_t)blockIdx.x*128 + ch] = s.x;
      partial[(size_t)blockIdx.x*128 + 64 + ch] = s.y;
    }
  }
}

// conv2: 128 pts/block, M=64, K=64; input = relu(scale1*z1+shift1) -> bf16
__global__ __launch_bounds__(256) void conv2_kernel(const unsigned short* __restrict__ z1,
    const float* __restrict__ w1, const float* __restrict__ b1,
    const float* __restrict__ scale1, const float* __restrict__ shift1,
    unsigned short* __restrict__ z2, float* __restrict__ partial){
  __shared__ unsigned short sa[128][72];
  __shared__ unsigned short swb[64][72];
  const int tid = threadIdx.x;
  const int p0 = blockIdx.x * 128;
  for (int i = tid; i < 64*32; i += 256){
    int o = i >> 5, c0 = (i & 31)*2;
    *(unsigned*)&swb[o][c0] = pack2(w1[o*64+c0], w1[o*64+c0+1]);
  }
  #pragma unroll
  for (int j=0;j<4;j++){
    int idx = tid + j*256;
    int pt = idx >> 3, cg = idx & 7;
    uint4 vv = *(const uint4*)(z1 + (size_t)(p0+pt)*64 + cg*8);
    unsigned a[4] = {vv.x, vv.y, vv.z, vv.w};
    unsigned r[4];
    #pragma unroll
    for (int t=0;t<4;t++){
      int c = cg*8 + t*2;
      float lo = __uint_as_float(a[t] << 16);
      float hi = __uint_as_float(a[t] & 0xFFFF0000u);
      float alo = fmaxf(lo*scale1[c]   + shift1[c],   0.f);
      float ahi = fmaxf(hi*scale1[c+1] + shift1[c+1], 0.f);
      r[t] = pack2(alo, ahi);
    }
    *(uint4*)&sa[pt][cg*8] = make_uint4(r[0],r[1],r[2],r[3]);
  }
  __syncthreads();
  const int wv = tid >> 6, lane = tid & 63;
  const int r15 = lane & 15, q = lane >> 4;
  f32x4 acc[8];
  #pragma unroll
  for (int t=0;t<8;t++) acc[t] = (f32x4){0.f,0.f,0.f,0.f};
  #pragma unroll
  for (int ks=0; ks<2; ks++){
    bf16x8 af = *(const bf16x8*)&swb[wv*16 + r15][ks*32 + q*8];
    #pragma unroll
    for (int t=0;t<8;t++){
      bf16x8 bfr = *(const bf16x8*)&sa[t*16 + r15][ks*32 + q*8];
      acc[t] = __builtin_amdgcn_mfma_f32_16x16x32_bf16(af, bfr, acc[t], 0,0,0);
    }
  }
  float bias[4];
  #pragma unroll
  for (int r=0;r<4;r++) bias[r] = b1[wv*16 + q*4 + r];
  f2 st[4];
  #pragma unroll
  for (int r=0;r<4;r++) st[r] = (f2){0.f,0.f};
  #pragma unroll
  for (int t=0;t<8;t++){
    float z0=acc[t][0]+bias[0], z1v=acc[t][1]+bias[1];
    float z2v=acc[t][2]+bias[2], z3v=acc[t][3]+bias[3];
    st[0] = pk_add(st[0], (f2){z0, z0*z0});
    st[1] = pk_add(st[1], (f2){z1v, z1v*z1v});
    st[2] = pk_add(st[2], (f2){z2v, z2v*z2v});
    st[3] = pk_add(st[3], (f2){z3v, z3v*z3v});
    *(uint2*)(z2 + (size_t)(p0 + t*16 + r15)*64 + wv*16 + q*4)
        = make_uint2(pack2(z0,z1v), pack2(z2v,z3v));
  }
  #pragma unroll
  for (int r=0;r<4;r++){
    f2 s = row16_sum_f2(st[r]);
    if (r15 == 15){
      int ch = wv*16 + q*4 + r;
      partial[(size_t)blockIdx.x*128 + ch] = s.x;
      partial[(size_t)blockIdx.x*128 + 64 + ch] = s.y;
    }
  }
}

// conv3: 128 pts (4 centers)/block, M=128, K=64; fused k-max (pre-BN valid:
// BN3 scale>0, density weight>=0); outputs m3 f32 + stats.
__global__ __launch_bounds__(256) void conv3_kernel(const unsigned short* __restrict__ z2,
    const float* __restrict__ w2, const float* __restrict__ b2,
    const float* __restrict__ scale2, const float* __restrict__ shift2,
    float* __restrict__ m3, float* __restrict__ partial){
  __shared__ unsigned short sa[128][72];
  __shared__ unsigned short swb[128][72];
  const int tid = threadIdx.x;
  const int p0 = blockIdx.x * 128;
  for (int i = tid; i < 128*32; i += 256){
    int o = i >> 5, c0 = (i & 31)*2;
    *(unsigned*)&swb[o][c0] = pack2(w2[o*64+c0], w2[o*64+c0+1]);
  }
  #pragma unroll
  for (int j=0;j<4;j++){
    int idx = tid + j*256;
    int pt = idx >> 3, cg = idx & 7;
    uint4 vv = *(const uint4*)(z2 + (size_t)(p0+pt)*64 + cg*8);
    unsigned a[4] = {vv.x, vv.y, vv.z, vv.w};
    unsigned r[4];
    #pragma unroll
    for (int t=0;t<4;t++){
      int c = cg*8 + t*2;
      float lo = __uint_as_float(a[t] << 16);
      float hi = __uint_as_float(a[t] & 0xFFFF0000u);
      float alo = fmaxf(lo*scale2[c]   + shift2[c],   0.f);
      float ahi = fmaxf(hi*scale2[c+1] + shift2[c+1], 0.f);
      r[t] = pack2(alo, ahi);
    }
    *(uint4*)&sa[pt][cg*8] = make_uint4(r[0],r[1],r[2],r[3]);
  }
  __syncthreads();
  const int wv = tid >> 6, lane = tid & 63;
  const int r15 = lane & 15, q = lane >> 4;
  f32x4 acc[2][8];
  #pragma unroll
  for (int mm=0;mm<2;mm++)
    #pragma unroll
    for (int t=0;t<8;t++) acc[mm][t] = (f32x4){0.f,0.f,0.f,0.f};
  #pragma unroll
  for (int ks=0; ks<2; ks++){
    bf16x8 af0 = *(const bf16x8*)&swb[(wv*2+0)*16 + r15][ks*32 + q*8];
    bf16x8 af1 = *(const bf16x8*)&swb[(wv*2+1)*16 + r15][ks*32 + q*8];
    #pragma unroll
    for (int t=0;t<8;t++){
      bf16x8 bfr = *(const bf16x8*)&sa[t*16 + r15][ks*32 + q*8];
      acc[0][t] = __builtin_amdgcn_mfma_f32_16x16x32_bf16(af0, bfr, acc[0][t], 0,0,0);
      acc[1][t] = __builtin_amdgcn_mfma_f32_16x16x32_bf16(af1, bfr, acc[1][t], 0,0,0);
    }
  }
  #pragma unroll
  for (int mm=0;mm<2;mm++){
    const int base = (wv*2+mm)*16;
    float bias[4];
    #pragma unroll
    for (int r=0;r<4;r++) bias[r] = b2[base + q*4 + r];
    float zv[8][4];
    f2 st[4];
    #pragma unroll
    for (int r=0;r<4;r++) st[r] = (f2){0.f,0.f};
    #pragma unroll
    for (int t=0;t<8;t++){
      #pragma unroll
      for (int r=0;r<4;r++){
        float z = acc[mm][t][r] + bias[r];
        zv[t][r] = z;
        st[r] = pk_add(st[r], (f2){z, z*z});
      }
    }
    #pragma unroll
    for (int r=0;r<4;r++){
      f2 s = row16_sum_f2(st[r]);
      if (r15 == 15){
        int ch = base + q*4 + r;
        partial[(size_t)blockIdx.x*256 + ch] = s.x;
        partial[(size_t)blockIdx.x*256 + 128 + ch] = s.y;
      }
    }
    #pragma unroll
    for (int c=0;c<4;c++){
      #pragma unroll
      for (int r=0;r<4;r++){
        float m = row16_max_f32(fmaxf(zv[2*c][r], zv[2*c+1][r]));
        if (r15 == 15)
          m3[(size_t)(blockIdx.x*4 + c)*128 + base + q*4 + r] = m;
      }
    }
  }
}

// reduce per-block partials -> BN scale/shift per channel
__global__ __launch_bounds__(256) void mkbn_kernel(const float* __restrict__ partial,
    int nrows, int stride, const float* __restrict__ g, const float* __restrict__ be,
    float* __restrict__ scale, float* __restrict__ shift, float inv_count){
  const int c = blockIdx.x;
  const int C = gridDim.x;
  float s=0.f, q=0.f;
  for (int r=threadIdx.x; r<nrows; r+=256){
    s += partial[(size_t)r*stride + c];
    q += partial[(size_t)r*stride + C + c];
  }
  __shared__ float ls[256], lq[256];
  ls[threadIdx.x]=s; lq[threadIdx.x]=q;
  __syncthreads();
  for (int off=128; off>0; off>>=1){
    if (threadIdx.x < off){ ls[threadIdx.x]+=ls[threadIdx.x+off]; lq[threadIdx.x]+=lq[threadIdx.x+off]; }
    __syncthreads();
  }
  if (threadIdx.x==0){
    float mean = ls[0]*inv_count;
    float var  = lq[0]*inv_count - mean*mean;
    float sc = g[c]*rsqrtf(var + EPSV);
    scale[c]=sc; shift[c]=be[c]-mean*sc;
  }
}

// out[b,ch,s] = relu(scale3*maxz + shift3) * relu(bn_d(wd*dcen+bd))
__global__ __launch_bounds__(256) void final_kernel(const float* __restrict__ m3,
    const float* __restrict__ dcen, const float* __restrict__ scale3,
    const float* __restrict__ shift3, const float* __restrict__ wd,
    const float* __restrict__ bd, const float* __restrict__ gd,
    const float* __restrict__ bed, const float* __restrict__ dstat,
    float* __restrict__ out){
  size_t i = (size_t)blockIdx.x*256 + threadIdx.x;
  int s  = (int)(i & 1023);
  int ch = (int)((i >> 10) & 127);
  int b  = (int)(i >> 17);
  float mean_d = dstat[0], var_d = dstat[1];
  float w = wd[ch];
  float meanp = w*mean_d + bd[ch];
  float varp  = w*w*var_d;
  float dsc = gd[ch]*rsqrtf(varp + EPSV);
  float dsh = bed[ch] - meanp*dsc;
  float pre = w*dcen[b*NS+s] + bd[ch];
  float dw  = fmaxf(dsc*pre + dsh, 0.0f);
  float z   = m3[((size_t)(b*NS+s))*128 + ch];
  float x   = fmaxf(scale3[ch]*z + shift3[ch], 0.0f);
  out[i] = x*dw;
}

// ---------------------------------------------------------------------------
extern "C" void kernel_launch(void* const* d_in, const int* in_sizes, int n_in,
                              void* d_out, int out_size, void* d_ws, size_t ws_size,
                              hipStream_t stream){
  const float* xyz     = (const float*)d_in[0];
  const float* points  = (const float*)d_in[1];
  const float* density = (const float*)d_in[2];
  const float* w0 = (const float*)d_in[3];
  const float* b0 = (const float*)d_in[4];
  const float* g0 = (const float*)d_in[5];
  const float* be0= (const float*)d_in[6];
  const float* w1 = (const float*)d_in[7];
  const float* b1 = (const float*)d_in[8];
  const float* g1 = (const float*)d_in[9];
  const float* be1= (const float*)d_in[10];
  const float* w2 = (const float*)d_in[11];
  const float* b2 = (const float*)d_in[12];
  const float* g2 = (const float*)d_in[13];
  const float* be2= (const float*)d_in[14];
  const float* wd = (const float*)d_in[15];
  const float* bd = (const float*)d_in[16];
  const float* gd = (const float*)d_in[17];
  const float* bed= (const float*)d_in[18];

  float* out = (float*)d_out;
  float* newxyz = out;                 // (B,S,3) = output 0
  float* out1   = out + (size_t)NB*NS*3;

  // workspace layout
  unsigned short* ptsT = (unsigned short*)d_ws;          // 4,194,304 u16
  float* sqx  = (float*)(ptsT + (size_t)NB*NN*NCF);      // 65,536 f
  int*   fidx = (int*)(sqx + (size_t)NB*NN);             // 16,384 i
  float* dcen = (float*)(fidx + NB*NS);                  // 16,384 f
  int*   kidx = (int*)(dcen + NB*NS);                    // 524,288 i
  unsigned short* z1 = (unsigned short*)(kidx + NPTS);   // 33,554,432 u16
  unsigned short* z2 = z1 + (size_t)NPTS*64;             // 33,554,432 u16
  float* m3   = (float*)(z2 + (size_t)NPTS*64);          // 2,097,152 f
  float* p1   = m3 + (size_t)NB*NS*128;                  // 4096*128 f
  float* p2   = p1 + 4096*128;                           // 4096*128 f
  float* p3   = p2 + 4096*128;                           // 4096*256 f
  float* bnp  = p3 + 4096*256;                           // 512 f
  float* dstat= bnp + 512;                               // 2 f

  hipLaunchKernelGGL(prep_kernel,  dim3(256),  dim3(256), 0, stream, points, xyz, ptsT, sqx);
  hipLaunchKernelGGL(fps_kernel,   dim3(NB),   dim3(FT),  0, stream, xyz, fidx, newxyz);
  hipLaunchKernelGGL(dcen_kernel,  dim3(64),   dim3(256), 0, stream, density, fidx, dcen);
  hipLaunchKernelGGL(dstats_kernel,dim3(1),    dim3(256), 0, stream, dcen, dstat);
  hipLaunchKernelGGL(knn_kernel,   dim3(4096), dim3(256), 0, stream, xyz, sqx, newxyz, kidx);
  hipLaunchKernelGGL(conv1_kernel, dim3(4096), dim3(256), 0, stream, xyz, ptsT, newxyz, kidx, w0, b0, z1, p1);
  hipLaunchKernelGGL(mkbn_kernel,  dim3(64),   dim3(256), 0, stream, p1, 4096, 128, g0, be0, bnp+0,   bnp+64,  1.0f/(float)NPTS);
  hipLaunchKernelGGL(conv2_kernel, dim3(4096), dim3(256), 0, stream, z1, w1, b1, bnp+0, bnp+64, z2, p2);
  hipLaunchKernelGGL(mkbn_kernel,  dim3(64),   dim3(256), 0, stream, p2, 4096, 128, g1, be1, bnp+128, bnp+192, 1.0f/(float)NPTS);
  hipLaunchKernelGGL(conv3_kernel, dim3(4096), dim3(256), 0, stream, z2, w2, b2, bnp+128, bnp+192, m3, p3);
  hipLaunchKernelGGL(mkbn_kernel,  dim3(128),  dim3(256), 0, stream, p3, 4096, 256, g2, be2, bnp+256, bnp+384, 1.0f/(float)NPTS);
  hipLaunchKernelGGL(final_kernel, dim3(8192), dim3(256), 0, stream, m3, dcen, bnp+256, bnp+384, wd, bd, gd, bed, dstat, out1);
}